// Round 11
// baseline (112.935 us; speedup 1.0000x reference)
//
#include <hip/hip_runtime.h>

#define NBOX   2048
#define MAXDET 100
#define NIMG   8
#define BLK    1024
#define POOL   512
// midpoint(0.3f, nextafterf(0.3f,+inf)) in double:
// RN_f32(inter/denom) > 0.3f  <=>  inter > IOU_MID * denom
// (25-bit mid x 24-bit denom product exact in f64; tie rounds-to-even to 0.3f -> "false" matches)
#define IOU_MID 0x1.333335p-2

typedef unsigned long long u64;

// in-register compare-exchange on r[8]; d = true means descending
#define CXR(a, b) { if (d ? (r[a] < r[b]) : (r[a] > r[b])) { u64 t_ = r[a]; r[a] = r[b]; r[b] = t_; } }

__device__ __forceinline__ u64 shx64(u64 v, int m) {
    int lo = __shfl_xor((int)(unsigned int)v, m, 64);
    int hi = __shfl_xor((int)(unsigned int)(v >> 32), m, 64);
    return ((u64)(unsigned int)hi << 32) | (unsigned int)lo;
}

__device__ __forceinline__ u64 readlane64(u64 v, int l) {
    unsigned int lo = (unsigned int)__builtin_amdgcn_readlane((int)(unsigned int)v, l);
    unsigned int hi = (unsigned int)__builtin_amdgcn_readlane((int)(v >> 32), l);
    return ((u64)hi << 32) | lo;
}

// bitonic in-register merge j=4,2,1 over the 8 keys, direction d
__device__ __forceinline__ void inregmerge(u64 r[8], bool d) {
    CXR(0, 4) CXR(1, 5) CXR(2, 6) CXR(3, 7)
    CXR(0, 2) CXR(1, 3) CXR(4, 6) CXR(5, 7)
    CXR(0, 1) CXR(2, 3) CXR(4, 5) CXR(6, 7)
}

// one shuffle exchange stage: element e = 8*lane + t, partner lane^m, phase k = 8*kb
__device__ __forceinline__ void shstage(u64 r[8], int lane, int kb, int m) {
#pragma unroll
    for (int t = 0; t < 8; ++t) {
        u64 p = shx64(r[t], m);
        bool tm = ((lane & kb) == 0) == ((lane & m) == 0);
        r[t] = ((r[t] > p) == tm) ? r[t] : p;
    }
}

// full descending bitonic sort of 512 keys held as r[8] across 64 lanes (e = 8*lane + t)
__device__ __forceinline__ void sort512(u64 r[8], int lane) {
    { bool d = true;  CXR(0, 1) }
    { bool d = false; CXR(2, 3) }
    { bool d = true;  CXR(4, 5) }
    { bool d = false; CXR(6, 7) }
    { bool d = true;  CXR(0, 2) CXR(1, 3) CXR(0, 1) CXR(2, 3) }
    { bool d = false; CXR(4, 6) CXR(5, 7) CXR(4, 5) CXR(6, 7) }
    inregmerge(r, (lane & 1) == 0);
#pragma unroll
    for (int k = 16; k <= 512; k <<= 1) {
        int kb = k >> 3;
#pragma unroll
        for (int m = kb >> 1; m >= 1; m >>= 1) shstage(r, lane, kb, m);
        inregmerge(r, (lane & kb) == 0);
    }
}

// descending merge of a bitonic 512-sequence held as r[8] across 64 lanes
__device__ __forceinline__ void bmerge512(u64 r[8], int lane) {
#pragma unroll
    for (int m = 32; m >= 1; m >>= 1) shstage(r, lane, 64, m);
    inregmerge(r, true);
}

__global__ __launch_bounds__(BLK) void region_extractor_kernel(
    const float* __restrict__ boxes,
    const float* __restrict__ scores,
    float* __restrict__ out)
{
    __shared__ u64    rawseg[NBOX];       // 16 KB: raw keys, then 4 sorted segments (tail)
    __shared__ u64    t01[1024];          // 8 KB: prune round-1 outputs
    __shared__ u64    top512[POOL];       // 4 KB: final sorted top-512 keys
    __shared__ float4 sbox[POOL];         // 8 KB: sorted top-512 boxes
    __shared__ u64    supRow[POOL * 8];   // 32 KB: suppression matrix (bits j>i only)
    __shared__ u64    validW[8];          // validity bitmask of top-512
    __shared__ float4 leadersB[MAXDET];   // kept boxes (tail state)
    __shared__ float  leadersA[MAXDET];   // kept areas

    const int g    = threadIdx.x;         // 0..1023
    const int lane = g & 63;
    const int wv   = g >> 6;              // 0..15
    const int b    = blockIdx.x;
    const float4* bb4 = (const float4*)(boxes + (size_t)b * NBOX * 4);
    const float*  ss  = scores + (size_t)b * NBOX;

    // Phase A: validity + composite sort key.
    // key = (score_bits << 32) | ~idx : desc sort == (score desc, idx asc);
    // invalid -> hi = 0 (sorts last, same as -inf). scores in [0,1): bits monotone.
    for (int p = 0; p < NBOX / BLK; ++p) {
        int i = p * BLK + g;
        float4 v = bb4[i];
        float  s = ss[i];
        bool valid = ((v.z - v.x) >= 25.0f) && ((v.w - v.y) >= 25.0f) && (s >= 0.001f);
        unsigned int sk = valid ? __float_as_uint(s) : 0u;
        rawseg[i] = ((u64)sk << 32) | (unsigned int)(~i);
    }
    __syncthreads();

    // Phase B1: waves 0..3 each shfl-sort one 512-segment descending (no barriers inside).
    if (wv < 4) {
        u64 r[8];
#pragma unroll
        for (int t = 0; t < 8; ++t) r[t] = rawseg[512 * wv + 8 * lane + t];
        sort512(r, lane);
#pragma unroll
        for (int t = 0; t < 8; ++t) rawseg[512 * wv + 8 * lane + t] = r[t];
    }
    __syncthreads();

    // Phase B2: prune-merge round 1. C[e] = max(A[e], B[511-e]) is the exact
    // top-512 multiset of A union B (both sorted desc, keys unique) and is bitonic.
    if (wv < 2) {
        const u64* segA = rawseg + 1024 * wv;
        u64 r[8];
#pragma unroll
        for (int t = 0; t < 8; ++t) {
            u64 a  = segA[8 * lane + t];
            u64 bb = segA[512 + 8 * (63 - lane) + (7 - t)];
            r[t] = (a > bb) ? a : bb;
        }
        bmerge512(r, lane);
#pragma unroll
        for (int t = 0; t < 8; ++t) t01[512 * wv + 8 * lane + t] = r[t];
    }
    __syncthreads();

    // Phase B3: prune-merge round 2 -> sorted top-512 of all 2048.
    if (wv == 0) {
        u64 r[8];
#pragma unroll
        for (int t = 0; t < 8; ++t) {
            u64 a  = t01[8 * lane + t];
            u64 bb = t01[512 + 8 * (63 - lane) + (7 - t)];
            r[t] = (a > bb) ? a : bb;
        }
        bmerge512(r, lane);
#pragma unroll
        for (int t = 0; t < 8; ++t) top512[8 * lane + t] = r[t];
    }
    __syncthreads();

    // Phase C: stage top-512 sorted boxes + validity words (waves 0..7).
    if (g < POOL) {
        u64 key = top512[g];
        unsigned int idx = ~(unsigned int)key;
        float4 v = bb4[idx];
        sbox[g] = v;
        u64 bal = __ballot((unsigned int)(key >> 32) != 0u);
        if (lane == 0) validW[wv] = bal;
    }
    __syncthreads();

    // Column cache: lane holds boxes at sorted positions 64*w + lane, w = 0..7.
    float4 cb[8];
    float  ca[8];
#pragma unroll
    for (int w = 0; w < 8; ++w) {
        float4 v = sbox[(w << 6) + lane];
        cb[w] = v;
        ca[w] = (v.z - v.x) * (v.w - v.y);
    }

    // Phase D1: parallel suppression-matrix build (R10, proven).
    // supRow[i][w] bit l = (64*w + l > i) && IoU(box_i, box_{64w+l}) > 0.3 (exact).
    // Words w < i>>6 left unwritten: the scan provably never reads them.
    for (int r = 0; r < POOL / 16; ++r) {
        int i = (r << 4) + wv;
        float4 Li = sbox[i];              // wave-uniform broadcast read
        float La = (Li.z - Li.x) * (Li.w - Li.y);
        int w0 = i >> 6;                  // wave-uniform
#pragma unroll
        for (int w = 0; w < 8; ++w) {
            if (w >= w0) {                // wave-uniform condition: ballot is safe
                int j0 = (w << 6) + lane;
                float iw = fminf(Li.z, cb[w].z) - fmaxf(Li.x, cb[w].x);
                float ih = fminf(Li.w, cb[w].w) - fmaxf(Li.y, cb[w].y);
                iw = fmaxf(iw, 0.0f);
                ih = fmaxf(ih, 0.0f);
                float inter = iw * ih;
                float denom = (La + ca[w]) - inter;   // ref op order: (a_i + a_j) - inter
                bool hit = (j0 > i) && ((double)inter > IOU_MID * (double)denom);
                u64 bits = __ballot(hit);
                if (lane == 0) supRow[(i << 3) + w] = bits;
            }
        }
    }
    __syncthreads();

    if (g >= 64) return;   // wave 0 finishes alone; no barriers below

    float* regions = out;
    float* maskv   = out + (size_t)NIMG * MAXDET * 5;
    int nkept = 0;

    // Phase D2: serial scan. Critical chain per keeper: ctz -> one UNIFORM
    // ds_read of the diagonal word (broadcast, no readlane) -> andn -> ctz.
    // Full-row fold into pend (future segments) runs off-chain in parallel lanes.
    u64 pend = 0;          // lane accumulates word (lane & 7)
    bool done = false;
    for (int s = 0; s < 8 && !done; ++s) {
        u64 mcur = validW[s] & ~readlane64(pend, s);
        while (mcur) {
            int il = (int)__builtin_ctzll(mcur);
            int i = (s << 6) + il;                     // next keeper in greedy order
            float4 Lb = sbox[i];                       // uniform (off the mask chain)
            if (lane == 0) {
                float* rr = regions + ((size_t)(b * MAXDET + nkept)) * 5;
                rr[0] = (float)b; rr[1] = Lb.x; rr[2] = Lb.y; rr[3] = Lb.z; rr[4] = Lb.w;
                maskv[b * MAXDET + nkept] = 1.0f;
                leadersB[nkept] = Lb;
                leadersA[nkept] = (Lb.z - Lb.x) * (Lb.w - Lb.y);
            }
            nkept++;
            if (nkept >= MAXDET) { done = true; break; }
            u64 rowS = supRow[(i << 3) + s];           // uniform broadcast (chain)
            u64 rowv = supRow[(i << 3) + (lane & 7)];  // off-chain full row
            pend |= rowv;
            mcur = (mcur & (mcur - 1)) & ~rowS;        // bits j<=i of rowS are 0 by build
        }
    }

    // Tail (exact, cold): candidates below poolMin in descending order via a
    // 4-way merge over the preserved sorted segments, tested vs kept leaders.
    if (nkept < MAXDET) {
        u64 poolMin = top512[POOL - 1];   // smallest pool key; key >= poolMin <=> in pool
        int q0 = 0, q1 = 0, q2 = 0, q3 = 0;
        while (q0 < 512 && rawseg[q0] >= poolMin) ++q0;
        while (q1 < 512 && rawseg[512 + q1] >= poolMin) ++q1;
        while (q2 < 512 && rawseg[1024 + q2] >= poolMin) ++q2;
        while (q3 < 512 && rawseg[1536 + q3] >= poolMin) ++q3;
        while (nkept < MAXDET) {
            u64 h0 = (q0 < 512) ? rawseg[q0] : 0;
            u64 h1 = (q1 < 512) ? rawseg[512 + q1] : 0;
            u64 h2 = (q2 < 512) ? rawseg[1024 + q2] : 0;
            u64 h3 = (q3 < 512) ? rawseg[1536 + q3] : 0;
            u64 m01 = (h0 > h1) ? h0 : h1;
            u64 m23 = (h2 > h3) ? h2 : h3;
            u64 hmax = (m01 > m23) ? m01 : m23;
            if ((unsigned int)(hmax >> 32) == 0u) break;   // exhausted / invalid
            if (hmax == h0) ++q0; else if (hmax == h1) ++q1;
            else if (hmax == h2) ++q2; else ++q3;
            unsigned int idx = ~(unsigned int)hmax;
            float4 v = bb4[idx];
            float varea = (v.z - v.x) * (v.w - v.y);
            bool sup = false;
            for (int t = lane; t < nkept; t += 64) {
                float4 Lb = leadersB[t];
                float  La = leadersA[t];
                float iw = fminf(Lb.z, v.z) - fmaxf(Lb.x, v.x);
                float ih = fminf(Lb.w, v.w) - fmaxf(Lb.y, v.y);
                iw = fmaxf(iw, 0.0f);
                ih = fmaxf(ih, 0.0f);
                float inter = iw * ih;
                float denom = (La + varea) - inter;
                if ((double)inter > IOU_MID * (double)denom) sup = true;
            }
            if (__ballot(sup) == 0ULL) {
                if (lane == 0) {
                    float* rr = regions + ((size_t)(b * MAXDET + nkept)) * 5;
                    rr[0] = (float)b; rr[1] = v.x; rr[2] = v.y; rr[3] = v.z; rr[4] = v.w;
                    maskv[b * MAXDET + nkept] = 1.0f;
                    leadersB[nkept] = v;
                    leadersA[nkept] = varea;
                }
                nkept++;
            }
        }
    }

    // Phase E: fill padding rows (d_out is poisoned before every launch).
    for (int r = nkept + lane; r < MAXDET; r += 64) {
        float* rr = regions + ((size_t)(b * MAXDET + r)) * 5;
        rr[0] = (float)b; rr[1] = 0.0f; rr[2] = 0.0f; rr[3] = 0.0f; rr[4] = 0.0f;
        maskv[b * MAXDET + r] = 0.0f;
    }
}

extern "C" void kernel_launch(void* const* d_in, const int* in_sizes, int n_in,
                              void* d_out, int out_size, void* d_ws, size_t ws_size,
                              hipStream_t stream) {
    const float* boxes  = (const float*)d_in[0];  // [8,2048,4] f32
    const float* scores = (const float*)d_in[1];  // [8,2048]   f32
    float* out = (float*)d_out;                   // 4800 f32: regions(4000) ++ mask(800)
    region_extractor_kernel<<<NIMG, BLK, 0, stream>>>(boxes, scores, out);
}

// Round 13
// 108.368 us; speedup vs baseline: 1.0421x; 1.0421x over previous
//
#include <hip/hip_runtime.h>

#define NBOX   2048
#define MAXDET 100
#define NIMG   8
#define BLK    1024
#define POOL   512
// midpoint(0.3f, nextafterf(0.3f,+inf)) in double:
// RN_f32(inter/denom) > 0.3f  <=>  inter > IOU_MID * denom
// (25-bit mid x 24-bit denom product exact in f64; tie rounds-to-even to 0.3f -> "false" matches)
#define IOU_MID 0x1.333335p-2

typedef unsigned long long u64;

__device__ __forceinline__ u64 shx64(u64 v, int m) {
    int lo = __shfl_xor((int)(unsigned int)v, m, 64);
    int hi = __shfl_xor((int)(unsigned int)(v >> 32), m, 64);
    return ((u64)(unsigned int)hi << 32) | (unsigned int)lo;
}

// bitonic keep rule: take_max ? max(mine, part) : min(mine, part); keys unique
__device__ __forceinline__ u64 cmpsel(u64 mine, u64 part, bool take_max) {
    return ((mine > part) == take_max) ? mine : part;
}

__device__ __forceinline__ u64 readlane64(u64 v, int l) {
    unsigned int lo = (unsigned int)__builtin_amdgcn_readlane((int)(unsigned int)v, l);
    unsigned int hi = (unsigned int)__builtin_amdgcn_readlane((int)(v >> 32), l);
    return ((u64)hi << 32) | lo;
}

__device__ __forceinline__ u64 mkkey(float4 v, float s, int i) {
    bool valid = ((v.z - v.x) >= 25.0f) && ((v.w - v.y) >= 25.0f) && (s >= 0.001f);
    unsigned int sk = valid ? __float_as_uint(s) : 0u;  // scores in [0,1): bits monotone
    return ((u64)sk << 32) | (unsigned int)(~i);
}

__global__ __launch_bounds__(BLK) void region_extractor_kernel(
    const float* __restrict__ boxes,
    const float* __restrict__ scores,
    float* __restrict__ out)
{
    __shared__ u64    bufA[NBOX];         // 16 KB; holds final sorted keys (desc)
    __shared__ u64    bufB[NBOX];         // 16 KB; sort double buffer
    __shared__ float4 sbox[POOL];         // 8 KB sorted top-512 boxes
    __shared__ u64    supRow[POOL * 8];   // 32 KB suppression matrix (bits j>i only)
    __shared__ u64    validW[8];          // validity bitmask of top-512
    __shared__ float4 leadersB[MAXDET];   // kept boxes (tail-path state)
    __shared__ float  leadersA[MAXDET];   // kept areas

    const int g    = threadIdx.x;         // 0..1023
    const int lane = g & 63;
    const int wv   = g >> 6;              // 0..15
    const int b    = blockIdx.x;
    const float4* bb4 = (const float4*)(boxes + (size_t)b * NBOX * 4);
    const float*  ss  = scores + (size_t)b * NBOX;

    // Phase A: build 2 keys/lane directly in registers; element e = 2*g + t.
    // key = (score_bits << 32) | ~idx : desc sort == (score desc, idx asc);
    // invalid -> hi = 0 (sorts last, same as -inf).
    const int e0 = 2 * g;
    u64 k0, k1;
    { float4 v = bb4[e0];     k0 = mkkey(v, ss[e0],     e0);     }
    { float4 v = bb4[e0 + 1]; k1 = mkkey(v, ss[e0 + 1], e0 + 1); }

    // Phase B: hybrid bitonic sort, descending. Element e = 128*wv + 2*lane + t.
    // j=1 in-register, j=2..64 intra-wave shuffles, j>=128 LDS (10 stages total).
    // Descending-region predicate for phase k (element units): (e & k) == 0,
    // which for e = 2g+t reduces to (g & (k/2)) == 0.  NOTE R12 BUG: used
    // (lane & KB) -- wrong for KB=64 (k=128), where the bit is g's bit 6
    // (wave parity), not a lane bit. Fixed: use g throughout.

    // k=2: direction from g bit 0
    { bool d = ((g & 1) == 0); if (d ? (k0 < k1) : (k0 > k1)) { u64 t_ = k0; k0 = k1; k1 = t_; } }

    // k = 4..128 element units <=> KB = k/2 = 2..64 in g units (intra-wave)
    for (int KB = 2; KB <= 64; KB <<= 1) {
        bool D = ((g & KB) == 0);                    // descending region (FIXED: g, not lane)
        for (int m = KB >> 1; m >= 1; m >>= 1) {     // shuffle stages j = 2m (m <= 32: lane bit)
            bool tm0 = (D == ((lane & m) == 0));
            k0 = cmpsel(k0, shx64(k0, m), tm0);
            k1 = cmpsel(k1, shx64(k1, m), tm0);
        }
        if (D ? (k0 < k1) : (k0 > k1)) { u64 t_ = k0; k0 = k1; k1 = t_; }   // j=1
    }

    // k = 256..2048: LDS stages for j >= 128, then intra-wave tail
    int sp = 0;                                      // LDS stage parity
    for (int K = 256; K <= 2048; K <<= 1) {
        bool D = ((e0 & K) == 0);                    // wave-uniform for K >= 256
        for (int j = K >> 1; j >= 128; j >>= 1) {
            u64* buf = (sp & 1) ? bufB : bufA;
            ++sp;
            buf[e0] = k0;                            // contiguous pair: one b128 write
            buf[e0 + 1] = k1;
            __syncthreads();
            int pe = e0 ^ j;                         // partner pair base (even)
            u64 p0 = buf[pe], p1 = buf[pe + 1];      // one b128 read
            bool tm = (D == ((e0 & j) == 0));        // wave-uniform
            k0 = cmpsel(k0, p0, tm);
            k1 = cmpsel(k1, p1, tm);
        }
        for (int m = 32; m >= 1; m >>= 1) {          // shuffle stages j = 64..2
            bool tm = (D == ((lane & m) == 0));
            k0 = cmpsel(k0, shx64(k0, m), tm);
            k1 = cmpsel(k1, shx64(k1, m), tm);
        }
        if (D ? (k0 < k1) : (k0 > k1)) { u64 t_ = k0; k0 = k1; k1 = t_; }   // j=1
    }

    // publish sorted keys (desc). Safe without extra barrier: the last LDS
    // stage's barrier (j=128 of K=2048, in bufB) fences all earlier bufA reads.
    bufA[e0] = k0;
    bufA[e0 + 1] = k1;
    __syncthreads();

    // Phase C: stage top-512 sorted boxes + validity words (waves 0..7).
    if (g < POOL) {
        u64 key = bufA[g];
        unsigned int idx = ~(unsigned int)key;
        float4 v = bb4[idx];
        sbox[g] = v;
        u64 bal = __ballot((unsigned int)(key >> 32) != 0u);
        if (lane == 0) validW[wv] = bal;
    }
    __syncthreads();

    // Column cache: lane holds boxes at sorted positions 64*w + lane, w = 0..7.
    float4 cb[8];
    float  ca[8];
#pragma unroll
    for (int w = 0; w < 8; ++w) {
        float4 v = sbox[(w << 6) + lane];
        cb[w] = v;
        ca[w] = (v.z - v.x) * (v.w - v.y);
    }

    // Phase D1: parallel suppression-matrix build (R10, proven).
    // supRow[i][w] bit l = (64*w + l > i) && IoU(box_i, box_{64w+l}) > 0.3 (exact).
    // Words w < i>>6 left unwritten: the scan provably never reads them.
    for (int r = 0; r < POOL / 16; ++r) {
        int i = (r << 4) + wv;
        float4 Li = sbox[i];              // wave-uniform broadcast read
        float La = (Li.z - Li.x) * (Li.w - Li.y);
        int w0 = i >> 6;                  // wave-uniform
#pragma unroll
        for (int w = 0; w < 8; ++w) {
            if (w >= w0) {                // wave-uniform condition: ballot is safe
                int j0 = (w << 6) + lane;
                float iw = fminf(Li.z, cb[w].z) - fmaxf(Li.x, cb[w].x);
                float ih = fminf(Li.w, cb[w].w) - fmaxf(Li.y, cb[w].y);
                iw = fmaxf(iw, 0.0f);
                ih = fmaxf(ih, 0.0f);
                float inter = iw * ih;
                float denom = (La + ca[w]) - inter;   // ref op order: (a_i + a_j) - inter
                bool hit = (j0 > i) && ((double)inter > IOU_MID * (double)denom);
                u64 bits = __ballot(hit);
                if (lane == 0) supRow[(i << 3) + w] = bits;
            }
        }
    }
    __syncthreads();

    if (g >= 64) return;   // wave 0 finishes alone; no barriers below

    float* regions = out;
    float* maskv   = out + (size_t)NIMG * MAXDET * 5;
    int nkept = 0;

    // Phase D2: serial scan. Chain per keeper: ctz -> uniform ds_read of the
    // diagonal word -> andn -> ctz. Full-row fold into pend runs off-chain.
    u64 pend = 0;          // lane accumulates word (lane & 7)
    bool done = false;
    for (int s = 0; s < 8 && !done; ++s) {
        u64 mcur = validW[s] & ~readlane64(pend, s);
        while (mcur) {
            int il = (int)__builtin_ctzll(mcur);
            int i = (s << 6) + il;                     // next keeper in greedy order
            float4 Lb = sbox[i];                       // uniform (off the mask chain)
            if (lane == 0) {
                float* rr = regions + ((size_t)(b * MAXDET + nkept)) * 5;
                rr[0] = (float)b; rr[1] = Lb.x; rr[2] = Lb.y; rr[3] = Lb.z; rr[4] = Lb.w;
                maskv[b * MAXDET + nkept] = 1.0f;
                leadersB[nkept] = Lb;
                leadersA[nkept] = (Lb.z - Lb.x) * (Lb.w - Lb.y);
            }
            nkept++;
            if (nkept >= MAXDET) { done = true; break; }
            u64 rowS = supRow[(i << 3) + s];           // uniform broadcast (chain)
            u64 rowv = supRow[(i << 3) + (lane & 7)];  // off-chain full row
            pend |= rowv;
            mcur = (mcur & (mcur - 1)) & ~rowS;        // bits j<=i of rowS are 0 by build
        }
    }

    // Tail (exact, cold): sorted positions >= POOL tested vs recorded leaders.
    // Greedy NMS suppression comes only from kept boxes, so this is sufficient.
    for (int pos = POOL; pos < NBOX && nkept < MAXDET; ++pos) {
        u64 key = bufA[pos];                           // uniform, sorted desc
        if ((unsigned int)(key >> 32) == 0u) break;    // invalids sort last
        unsigned int idx = ~(unsigned int)key;
        float4 v = bb4[idx];
        float varea = (v.z - v.x) * (v.w - v.y);
        bool sup = false;
        for (int t = lane; t < nkept; t += 64) {
            float4 Lb = leadersB[t];
            float  La = leadersA[t];
            float iw = fminf(Lb.z, v.z) - fmaxf(Lb.x, v.x);
            float ih = fminf(Lb.w, v.w) - fmaxf(Lb.y, v.y);
            iw = fmaxf(iw, 0.0f);
            ih = fmaxf(ih, 0.0f);
            float inter = iw * ih;
            float denom = (La + varea) - inter;
            if ((double)inter > IOU_MID * (double)denom) sup = true;
        }
        if (__ballot(sup) == 0ULL) {
            if (lane == 0) {
                float* rr = regions + ((size_t)(b * MAXDET + nkept)) * 5;
                rr[0] = (float)b; rr[1] = v.x; rr[2] = v.y; rr[3] = v.z; rr[4] = v.w;
                maskv[b * MAXDET + nkept] = 1.0f;
                leadersB[nkept] = v;
                leadersA[nkept] = varea;
            }
            nkept++;
        }
    }

    // Phase E: fill padding rows (d_out is poisoned before every launch).
    for (int r = nkept + lane; r < MAXDET; r += 64) {
        float* rr = regions + ((size_t)(b * MAXDET + r)) * 5;
        rr[0] = (float)b; rr[1] = 0.0f; rr[2] = 0.0f; rr[3] = 0.0f; rr[4] = 0.0f;
        maskv[b * MAXDET + r] = 0.0f;
    }
}

extern "C" void kernel_launch(void* const* d_in, const int* in_sizes, int n_in,
                              void* d_out, int out_size, void* d_ws, size_t ws_size,
                              hipStream_t stream) {
    const float* boxes  = (const float*)d_in[0];  // [8,2048,4] f32
    const float* scores = (const float*)d_in[1];  // [8,2048]   f32
    float* out = (float*)d_out;                   // 4800 f32: regions(4000) ++ mask(800)
    region_extractor_kernel<<<NIMG, BLK, 0, stream>>>(boxes, scores, out);
}

// Round 14
// 96.381 us; speedup vs baseline: 1.1718x; 1.1244x over previous
//
#include <hip/hip_runtime.h>

#define NBOX   2048
#define HALF   1024
#define MAXDET 100
#define NIMG   8
#define POOL   512
// midpoint(0.3f, nextafterf(0.3f,+inf)) in double:
// RN_f32(inter/denom) > 0.3f  <=>  inter > IOU_MID * denom
// (25-bit mid x 24-bit denom product exact in f64; tie rounds-to-even to 0.3f -> "false" matches)
#define IOU_MID 0x1.333335p-2

typedef unsigned long long u64;

// d_ws layout (bytes); total 459328 (assumes ws_size >= 512 KB)
#define WS_HK   0        // u64 halfKeys[8][2048]: two sorted desc 1024-halves/image
#define WS_SBOX 131072   // float4 gsbox[8][512]: sorted top-512 boxes
#define WS_VAL  196608   // u64 gvalid[8][8]
#define WS_PMIN 197120   // u64 gpmin[8]: smallest pool key
#define WS_SUP  197184   // u64 gsup[8][512*8]: suppression matrix

__device__ __forceinline__ u64 shx64(u64 v, int m) {
    int lo = __shfl_xor((int)(unsigned int)v, m, 64);
    int hi = __shfl_xor((int)(unsigned int)(v >> 32), m, 64);
    return ((u64)(unsigned int)hi << 32) | (unsigned int)lo;
}
// bitonic keep rule: take_max ? max(mine, part) : min(mine, part); keys unique
__device__ __forceinline__ u64 cmpsel(u64 mine, u64 part, bool take_max) {
    return ((mine > part) == take_max) ? mine : part;
}
__device__ __forceinline__ u64 readlane64(u64 v, int l) {
    unsigned int lo = (unsigned int)__builtin_amdgcn_readlane((int)(unsigned int)v, l);
    unsigned int hi = (unsigned int)__builtin_amdgcn_readlane((int)(v >> 32), l);
    return ((u64)hi << 32) | lo;
}
__device__ __forceinline__ u64 mkkey(float4 v, float s, int i) {
    bool valid = ((v.z - v.x) >= 25.0f) && ((v.w - v.y) >= 25.0f) && (s >= 0.001f);
    unsigned int sk = valid ? __float_as_uint(s) : 0u;  // scores in [0,1): bits monotone
    return ((u64)sk << 32) | (unsigned int)(~i);
}

// K1: 16 blocks x 512 thr. Block sorts one 1024-box half descending (R13 hybrid:
// j=1 reg, j=2..64 shuffle, j>=128 LDS -> 6 LDS stages). Element e = 2*g + t.
__global__ __launch_bounds__(512) void k_sort_half(
    const float* __restrict__ boxes, const float* __restrict__ scores,
    u64* __restrict__ halfKeys)
{
    __shared__ u64 bufA[HALF], bufB[HALF];
    const int g    = threadIdx.x;        // 0..511
    const int lane = g & 63;
    const int img  = blockIdx.x >> 1;
    const int half = blockIdx.x & 1;
    const float4* bb4 = (const float4*)boxes + (img * NBOX + half * HALF);
    const float*  ss  = scores + (img * NBOX + half * HALF);

    const int e0 = 2 * g;
    u64 k0, k1;
    { float4 v = bb4[e0];     k0 = mkkey(v, ss[e0],     half * HALF + e0);     }
    { float4 v = bb4[e0 + 1]; k1 = mkkey(v, ss[e0 + 1], half * HALF + e0 + 1); }

    // k=2: direction from g bit 0
    { bool D = ((g & 1) == 0); if (D ? (k0 < k1) : (k0 > k1)) { u64 t_ = k0; k0 = k1; k1 = t_; } }
    // k = 4..128 element units <=> KB = 2..64 in g units (intra-wave)
    for (int KB = 2; KB <= 64; KB <<= 1) {
        bool D = ((g & KB) == 0);                    // descending-region bit of g
        for (int m = KB >> 1; m >= 1; m >>= 1) {
            bool tm = (D == ((lane & m) == 0));
            k0 = cmpsel(k0, shx64(k0, m), tm);
            k1 = cmpsel(k1, shx64(k1, m), tm);
        }
        if (D ? (k0 < k1) : (k0 > k1)) { u64 t_ = k0; k0 = k1; k1 = t_; }
    }
    // K = 256..1024: LDS stages for j >= 128, then intra-wave tail
    int sp = 0;
    for (int K = 256; K <= 1024; K <<= 1) {
        bool D = ((e0 & K) == 0);                    // wave-uniform (g bits 7..9)
        for (int j = K >> 1; j >= 128; j >>= 1) {
            u64* buf = (sp & 1) ? bufB : bufA;
            ++sp;
            buf[e0] = k0; buf[e0 + 1] = k1;
            __syncthreads();
            int pe = e0 ^ j;
            u64 p0 = buf[pe], p1 = buf[pe + 1];
            bool tm = (D == ((e0 & j) == 0));        // wave-uniform
            k0 = cmpsel(k0, p0, tm);
            k1 = cmpsel(k1, p1, tm);
        }
        for (int m = 32; m >= 1; m >>= 1) {
            bool tm = (D == ((lane & m) == 0));
            k0 = cmpsel(k0, shx64(k0, m), tm);
            k1 = cmpsel(k1, shx64(k1, m), tm);
        }
        if (D ? (k0 < k1) : (k0 > k1)) { u64 t_ = k0; k0 = k1; k1 = t_; }
    }
    u64* dst = halfKeys + (img * NBOX + half * HALF);
    dst[e0] = k0; dst[e0 + 1] = k1;
}

// K2: 8 blocks x 512 thr. Exact top-512 of the two sorted halves via prune-merge
// (R11-validated): C[e] = max(A[e], B[511-e]) is the top-512 multiset and bitonic;
// then a descending bitonic merge (3 LDS + 6 shuffle stages). Stage boxes/valid/pmin.
__global__ __launch_bounds__(512) void k_merge_top(
    const float* __restrict__ boxes, const u64* __restrict__ halfKeys,
    float4* __restrict__ gsbox, u64* __restrict__ gvalid, u64* __restrict__ gpmin)
{
    __shared__ u64 mA[POOL], mB[POOL];
    const int e    = threadIdx.x;        // rank slot 0..511
    const int lane = e & 63;
    const int img  = blockIdx.x;
    const u64* hk = halfKeys + img * NBOX;

    u64 a  = hk[e];
    u64 bq = hk[HALF + (POOL - 1 - e)];
    u64 c  = (a > bq) ? a : bq;
    // descending bitonic merge: take_max iff (e & j) == 0
    mA[e] = c; __syncthreads();
    c = cmpsel(c, mA[e ^ 256], (e & 256) == 0);
    mB[e] = c; __syncthreads();
    c = cmpsel(c, mB[e ^ 128], (e & 128) == 0);
    mA[e] = c; __syncthreads();
    c = cmpsel(c, mA[e ^ 64], (e & 64) == 0);
    for (int m = 32; m >= 1; m >>= 1)
        c = cmpsel(c, shx64(c, m), (lane & m) == 0);

    unsigned int idx = ~(unsigned int)c;             // original index in image
    float4 v = ((const float4*)boxes + img * NBOX)[idx];
    gsbox[img * POOL + e] = v;
    u64 bal = __ballot(((unsigned int)(c >> 32)) != 0u);
    if (lane == 0) gvalid[img * 8 + (e >> 6)] = bal;
    if (e == POOL - 1) gpmin[img] = c;
}

// K3: 64 blocks x 256 thr (8 blocks/image). Suppression-matrix build over 64 CUs.
// supRow[i][w] bit l = (64w+l > i) && IoU(box_i, box_{64w+l}) > 0.3 (exact f64 midpoint).
// Words w < i>>6 left unwritten (never read by the scan's consuming pattern).
__global__ __launch_bounds__(256) void k_build_matrix(
    const float4* __restrict__ gsbox, u64* __restrict__ gsup)
{
    __shared__ float4 lsbox[POOL];
    const int tid  = threadIdx.x;        // 0..255
    const int lane = tid & 63;
    const int wvL  = tid >> 6;           // 0..3
    const int img  = blockIdx.x >> 3;
    const int sl   = blockIdx.x & 7;
    const float4* src = gsbox + img * POOL;
    lsbox[tid] = src[tid];
    lsbox[tid + 256] = src[tid + 256];
    __syncthreads();

    float4 cb[8]; float ca[8];
#pragma unroll
    for (int w = 0; w < 8; ++w) {
        float4 v = lsbox[(w << 6) + lane];
        cb[w] = v; ca[w] = (v.z - v.x) * (v.w - v.y);
    }
    u64* sup = gsup + (size_t)img * (POOL * 8);
    for (int r = 0; r < 16; ++r) {
        int i = (r << 5) + (sl << 2) + wvL;          // balanced triangle coverage
        float4 Li = lsbox[i];
        float La = (Li.z - Li.x) * (Li.w - Li.y);
        int w0 = i >> 6;                             // wave-uniform
#pragma unroll
        for (int w = 0; w < 8; ++w) {
            if (w >= w0) {                           // wave-uniform: ballot safe
                int j0 = (w << 6) + lane;
                float iw = fminf(Li.z, cb[w].z) - fmaxf(Li.x, cb[w].x);
                float ih = fminf(Li.w, cb[w].w) - fmaxf(Li.y, cb[w].y);
                iw = fmaxf(iw, 0.0f); ih = fmaxf(ih, 0.0f);
                float inter = iw * ih;
                float denom = (La + ca[w]) - inter;  // ref op order: (a_i + a_j) - inter
                bool hit = (j0 > i) && ((double)inter > IOU_MID * (double)denom);
                u64 bits = __ballot(hit);
                if (lane == 0) sup[(i << 3) + w] = bits;
            }
        }
    }
}

// K4: 8 blocks x 1024. Copy matrix/boxes to LDS, then wave-0 serial scan (R13,
// proven), 2-way-merge tail over sorted halves (R11 pattern), padding fill.
__global__ __launch_bounds__(1024) void k_scan(
    const float* __restrict__ boxes, const u64* __restrict__ halfKeys,
    const float4* __restrict__ gsbox, const u64* __restrict__ gvalid,
    const u64* __restrict__ gpmin, const u64* __restrict__ gsup,
    float* __restrict__ out)
{
    __shared__ u64    supRow[POOL * 8];   // 32 KB
    __shared__ float4 sbox[POOL];         // 8 KB
    __shared__ u64    validW[8];
    __shared__ float4 leadersB[MAXDET];
    __shared__ float  leadersA[MAXDET];

    const int g    = threadIdx.x;
    const int lane = g & 63;
    const int img  = blockIdx.x;

    const u64* supg = gsup + (size_t)img * (POOL * 8);
#pragma unroll
    for (int t = 0; t < 4; ++t) supRow[g + t * 1024] = supg[g + t * 1024];
    if (g < POOL) sbox[g] = gsbox[img * POOL + g];
    if (g < 8)    validW[g] = gvalid[img * 8 + g];
    __syncthreads();

    if (g >= 64) return;   // wave 0 finishes alone; no barriers below

    float* regions = out;
    float* maskv   = out + (size_t)NIMG * MAXDET * 5;
    int nkept = 0;

    // serial scan: chain per keeper = ctz -> uniform ds_read of diagonal word ->
    // andn -> ctz; full-row fold into pend runs off-chain in parallel lanes.
    u64 pend = 0;          // lane accumulates word (lane & 7)
    bool done = false;
    for (int s = 0; s < 8 && !done; ++s) {
        u64 mcur = validW[s] & ~readlane64(pend, s);
        while (mcur) {
            int il = (int)__builtin_ctzll(mcur);
            int i = (s << 6) + il;                     // next keeper in greedy order
            float4 Lb = sbox[i];                       // uniform (off the mask chain)
            if (lane == 0) {
                float* rr = regions + ((size_t)(img * MAXDET + nkept)) * 5;
                rr[0] = (float)img; rr[1] = Lb.x; rr[2] = Lb.y; rr[3] = Lb.z; rr[4] = Lb.w;
                maskv[img * MAXDET + nkept] = 1.0f;
                leadersB[nkept] = Lb;
                leadersA[nkept] = (Lb.z - Lb.x) * (Lb.w - Lb.y);
            }
            nkept++;
            if (nkept >= MAXDET) { done = true; break; }
            u64 rowS = supRow[(i << 3) + s];           // uniform broadcast (chain)
            u64 rowv = supRow[(i << 3) + (lane & 7)];  // off-chain full row
            pend |= rowv;
            mcur = (mcur & (mcur - 1)) & ~rowS;        // bits j<=i of rowS are 0 by build
        }
    }

    // Tail (exact, cold): keys below poolMin in desc order via 2-way merge of
    // the sorted halves, each candidate tested vs recorded leaders (sufficient
    // state: greedy NMS suppression comes only from kept boxes).
    if (nkept < MAXDET) {
        const u64* hk = halfKeys + img * NBOX;
        const float4* bb4 = (const float4*)boxes + img * NBOX;
        u64 pmin = gpmin[img];                         // pool = keys >= pmin
        int q0 = 0, q1 = 0;
        while (q0 < HALF && hk[q0] >= pmin) ++q0;
        while (q1 < HALF && hk[HALF + q1] >= pmin) ++q1;
        while (nkept < MAXDET) {
            u64 h0 = (q0 < HALF) ? hk[q0] : 0;
            u64 h1 = (q1 < HALF) ? hk[HALF + q1] : 0;
            u64 hmax = (h0 > h1) ? h0 : h1;
            if ((unsigned int)(hmax >> 32) == 0u) break;   // invalids sort last
            if (hmax == h0) ++q0; else ++q1;
            unsigned int idx = ~(unsigned int)hmax;
            float4 v = bb4[idx];
            float varea = (v.z - v.x) * (v.w - v.y);
            bool sup = false;
            for (int t = lane; t < nkept; t += 64) {
                float4 Lb = leadersB[t];
                float  La = leadersA[t];
                float iw = fminf(Lb.z, v.z) - fmaxf(Lb.x, v.x);
                float ih = fminf(Lb.w, v.w) - fmaxf(Lb.y, v.y);
                iw = fmaxf(iw, 0.0f); ih = fmaxf(ih, 0.0f);
                float inter = iw * ih;
                float denom = (La + varea) - inter;
                if ((double)inter > IOU_MID * (double)denom) sup = true;
            }
            if (__ballot(sup) == 0ULL) {
                if (lane == 0) {
                    float* rr = regions + ((size_t)(img * MAXDET + nkept)) * 5;
                    rr[0] = (float)img; rr[1] = v.x; rr[2] = v.y; rr[3] = v.z; rr[4] = v.w;
                    maskv[img * MAXDET + nkept] = 1.0f;
                    leadersB[nkept] = v;
                    leadersA[nkept] = varea;
                }
                nkept++;
            }
        }
    }

    // padding fill (d_out is poisoned before every launch)
    for (int r = nkept + lane; r < MAXDET; r += 64) {
        float* rr = regions + ((size_t)(img * MAXDET + r)) * 5;
        rr[0] = (float)img; rr[1] = 0.0f; rr[2] = 0.0f; rr[3] = 0.0f; rr[4] = 0.0f;
        maskv[img * MAXDET + r] = 0.0f;
    }
}

extern "C" void kernel_launch(void* const* d_in, const int* in_sizes, int n_in,
                              void* d_out, int out_size, void* d_ws, size_t ws_size,
                              hipStream_t stream) {
    const float* boxes  = (const float*)d_in[0];  // [8,2048,4] f32
    const float* scores = (const float*)d_in[1];  // [8,2048]   f32
    float* out = (float*)d_out;                   // 4800 f32: regions(4000) ++ mask(800)
    char* ws = (char*)d_ws;
    u64*    halfKeys = (u64*)(ws + WS_HK);
    float4* gsbox    = (float4*)(ws + WS_SBOX);
    u64*    gvalid   = (u64*)(ws + WS_VAL);
    u64*    gpmin    = (u64*)(ws + WS_PMIN);
    u64*    gsup     = (u64*)(ws + WS_SUP);

    k_sort_half<<<16, 512, 0, stream>>>(boxes, scores, halfKeys);
    k_merge_top<<<NIMG, 512, 0, stream>>>(boxes, halfKeys, gsbox, gvalid, gpmin);
    k_build_matrix<<<64, 256, 0, stream>>>(gsbox, gsup);
    k_scan<<<NIMG, 1024, 0, stream>>>(boxes, halfKeys, gsbox, gvalid, gpmin, gsup, out);
}

// Round 15
// 86.271 us; speedup vs baseline: 1.3091x; 1.1172x over previous
//
#include <hip/hip_runtime.h>

#define NBOX   2048
#define HALF   1024
#define MAXDET 100
#define NIMG   8
#define POOL   256
// midpoint(0.3f, nextafterf(0.3f,+inf)) in double:
// RN_f32(inter/denom) > 0.3f  <=>  inter > IOU_MID * denom
// (25-bit mid x 24-bit denom product exact in f64; tie rounds-to-even to 0.3f -> "false" matches)
#define IOU_MID 0x1.333335p-2

typedef unsigned long long u64;

__device__ __forceinline__ u64 shx64(u64 v, int m) {
    int lo = __shfl_xor((int)(unsigned int)v, m, 64);
    int hi = __shfl_xor((int)(unsigned int)(v >> 32), m, 64);
    return ((u64)(unsigned int)hi << 32) | (unsigned int)lo;
}
// bitonic keep rule: take_max ? max(mine, part) : min(mine, part); keys unique
__device__ __forceinline__ u64 cmpsel(u64 mine, u64 part, bool take_max) {
    return ((mine > part) == take_max) ? mine : part;
}
__device__ __forceinline__ u64 readlane64(u64 v, int l) {
    unsigned int lo = (unsigned int)__builtin_amdgcn_readlane((int)(unsigned int)v, l);
    unsigned int hi = (unsigned int)__builtin_amdgcn_readlane((int)(v >> 32), l);
    return ((u64)hi << 32) | lo;
}
__device__ __forceinline__ u64 mkkey(float4 v, float s, int i) {
    bool valid = ((v.z - v.x) >= 25.0f) && ((v.w - v.y) >= 25.0f) && (s >= 0.001f);
    unsigned int sk = valid ? __float_as_uint(s) : 0u;  // scores in [0,1): bits monotone
    return ((u64)sk << 32) | (unsigned int)(~i);
}

// K1: 16 blocks x 512 thr. Block sorts one 1024-box half descending (proven R14:
// j=1 reg, j=2..64 shuffle, j>=128 LDS -> 6 LDS stages). Element e = 2*g + t.
__global__ __launch_bounds__(512) void k_sort_half(
    const float* __restrict__ boxes, const float* __restrict__ scores,
    u64* __restrict__ halfKeys)
{
    __shared__ u64 bufA[HALF], bufB[HALF];
    const int g    = threadIdx.x;        // 0..511
    const int lane = g & 63;
    const int img  = blockIdx.x >> 1;
    const int half = blockIdx.x & 1;
    const float4* bb4 = (const float4*)boxes + (img * NBOX + half * HALF);
    const float*  ss  = scores + (img * NBOX + half * HALF);

    const int e0 = 2 * g;
    u64 k0, k1;
    { float4 v = bb4[e0];     k0 = mkkey(v, ss[e0],     half * HALF + e0);     }
    { float4 v = bb4[e0 + 1]; k1 = mkkey(v, ss[e0 + 1], half * HALF + e0 + 1); }

    // k=2: direction from g bit 0
    { bool D = ((g & 1) == 0); if (D ? (k0 < k1) : (k0 > k1)) { u64 t_ = k0; k0 = k1; k1 = t_; } }
    // k = 4..128 element units <=> KB = 2..64 in g units (intra-wave)
    for (int KB = 2; KB <= 64; KB <<= 1) {
        bool D = ((g & KB) == 0);                    // descending-region bit of g
        for (int m = KB >> 1; m >= 1; m >>= 1) {
            bool tm = (D == ((lane & m) == 0));
            k0 = cmpsel(k0, shx64(k0, m), tm);
            k1 = cmpsel(k1, shx64(k1, m), tm);
        }
        if (D ? (k0 < k1) : (k0 > k1)) { u64 t_ = k0; k0 = k1; k1 = t_; }
    }
    // K = 256..1024: LDS stages for j >= 128, then intra-wave tail
    int sp = 0;
    for (int K = 256; K <= 1024; K <<= 1) {
        bool D = ((e0 & K) == 0);                    // wave-uniform (g bits 7..9)
        for (int j = K >> 1; j >= 128; j >>= 1) {
            u64* buf = (sp & 1) ? bufB : bufA;
            ++sp;
            buf[e0] = k0; buf[e0 + 1] = k1;
            __syncthreads();
            int pe = e0 ^ j;
            u64 p0 = buf[pe], p1 = buf[pe + 1];
            bool tm = (D == ((e0 & j) == 0));        // wave-uniform
            k0 = cmpsel(k0, p0, tm);
            k1 = cmpsel(k1, p1, tm);
        }
        for (int m = 32; m >= 1; m >>= 1) {
            bool tm = (D == ((lane & m) == 0));
            k0 = cmpsel(k0, shx64(k0, m), tm);
            k1 = cmpsel(k1, shx64(k1, m), tm);
        }
        if (D ? (k0 < k1) : (k0 > k1)) { u64 t_ = k0; k0 = k1; k1 = t_; }
    }
    u64* dst = halfKeys + (img * NBOX + half * HALF);
    dst[e0] = k0; dst[e0 + 1] = k1;
}

// K2: 8 blocks x 1024 (one per image). Fused: top-256 prune-merge -> suppression
// matrix (256 rows x <=4 words, 16 waves) -> wave-0 serial scan -> exact tail.
__global__ __launch_bounds__(1024) void k_nms(
    const float* __restrict__ boxes, const u64* __restrict__ halfKeys,
    float* __restrict__ out)
{
    __shared__ u64    supRow[POOL * 4];   // 8 KB suppression matrix (bits j>i only)
    __shared__ float4 sbox[POOL];         // 4 KB sorted top-256 boxes
    __shared__ u64    mA[POOL], mB[POOL]; // merge scratch
    __shared__ u64    validW[4];          // validity bitmask of top-256
    __shared__ u64    pminS;              // smallest pool key
    __shared__ float4 leadersB[MAXDET];   // kept boxes (tail state)
    __shared__ float  leadersA[MAXDET];   // kept areas

    const int g    = threadIdx.x;         // 0..1023
    const int lane = g & 63;
    const int wv   = g >> 6;              // 0..15
    const int img  = blockIdx.x;
    const u64* hk = halfKeys + img * NBOX;
    const float4* bb4 = (const float4*)boxes + img * NBOX;

    // Top-256 prune-merge (R11/R14-validated identity at K=256): both halves
    // sorted desc with unique keys, so top-256 of the union uses only the first
    // 256 of each, and C[e] = max(A[e], B[255-e]) is that multiset, bitonic.
    // Then descending bitonic merge: take_max iff (e & j) == 0; j=128,64 via LDS.
    u64 c = 0;
    if (g < POOL) {
        u64 a  = hk[g];
        u64 bq = hk[HALF + (POOL - 1 - g)];
        c = (a > bq) ? a : bq;
        mA[g] = c;
    }
    __syncthreads();
    if (g < POOL) { c = cmpsel(c, mA[g ^ 128], (g & 128) == 0); mB[g] = c; }
    __syncthreads();
    if (g < POOL) {                      // waves 0..3 fully active: ballot safe
        c = cmpsel(c, mB[g ^ 64], (g & 64) == 0);
        for (int m = 32; m >= 1; m >>= 1)
            c = cmpsel(c, shx64(c, m), (lane & m) == 0);
        unsigned int idx = ~(unsigned int)c;
        float4 v = bb4[idx];
        sbox[g] = v;
        u64 bal = __ballot(((unsigned int)(c >> 32)) != 0u);
        if (lane == 0) validW[wv] = bal;
        if (g == POOL - 1) pminS = c;
    }
    __syncthreads();

    // Column cache: lane holds boxes at sorted positions 64*w + lane, w = 0..3.
    float4 cb[4];
    float  ca[4];
#pragma unroll
    for (int w = 0; w < 4; ++w) {
        float4 v = sbox[(w << 6) + lane];
        cb[w] = v;
        ca[w] = (v.z - v.x) * (v.w - v.y);
    }

    // Matrix build (R10-proven row math): wave wv owns rows i = 16*r + wv.
    // supRow[i][w] bit l = (64w+l > i) && IoU(box_i, box_{64w+l}) > 0.3 (exact).
    // Words w < i>>6 left unwritten; the scan provably never consumes them
    // (pend word w is only read at entry to segment w, after which only rows
    // with i >= 64*w -- whose word w IS written -- are folded).
    for (int r = 0; r < POOL / 16; ++r) {
        int i = (r << 4) + wv;
        float4 Li = sbox[i];              // wave-uniform broadcast read
        float La = (Li.z - Li.x) * (Li.w - Li.y);
        int w0 = i >> 6;                  // wave-uniform
#pragma unroll
        for (int w = 0; w < 4; ++w) {
            if (w >= w0) {                // wave-uniform condition: ballot safe
                int j0 = (w << 6) + lane;
                float iw = fminf(Li.z, cb[w].z) - fmaxf(Li.x, cb[w].x);
                float ih = fminf(Li.w, cb[w].w) - fmaxf(Li.y, cb[w].y);
                iw = fmaxf(iw, 0.0f);
                ih = fmaxf(ih, 0.0f);
                float inter = iw * ih;
                float denom = (La + ca[w]) - inter;   // ref op order: (a_i + a_j) - inter
                bool hit = (j0 > i) && ((double)inter > IOU_MID * (double)denom);
                u64 bits = __ballot(hit);
                if (lane == 0) supRow[(i << 2) + w] = bits;
            }
        }
    }
    __syncthreads();

    if (g >= 64) return;   // wave 0 finishes alone; no barriers below

    float* regions = out;
    float* maskv   = out + (size_t)NIMG * MAXDET * 5;
    int nkept = 0;

    // Serial scan (R13-proven): chain per keeper = ctz -> uniform ds_read of the
    // diagonal word -> andn -> ctz. Full-row fold into pend runs off-chain.
    u64 pend = 0;          // lane accumulates word (lane & 3)
    bool done = false;
    for (int s = 0; s < 4 && !done; ++s) {
        u64 mcur = validW[s] & ~readlane64(pend, s);
        while (mcur) {
            int il = (int)__builtin_ctzll(mcur);
            int i = (s << 6) + il;                     // next keeper in greedy order
            float4 Lb = sbox[i];                       // uniform (off the mask chain)
            if (lane == 0) {
                float* rr = regions + ((size_t)(img * MAXDET + nkept)) * 5;
                rr[0] = (float)img; rr[1] = Lb.x; rr[2] = Lb.y; rr[3] = Lb.z; rr[4] = Lb.w;
                maskv[img * MAXDET + nkept] = 1.0f;
                leadersB[nkept] = Lb;
                leadersA[nkept] = (Lb.z - Lb.x) * (Lb.w - Lb.y);
            }
            nkept++;
            if (nkept >= MAXDET) { done = true; break; }
            u64 rowS = supRow[(i << 2) + s];           // uniform broadcast (chain)
            u64 rowv = supRow[(i << 2) + (lane & 3)];  // off-chain full row
            pend |= rowv;
            mcur = (mcur & (mcur - 1)) & ~rowS;        // bits j<=i of rowS are 0 by build
        }
    }

    // Tail (exact, cold): keys below poolMin in desc order via 2-way merge of
    // the sorted halves, tested vs recorded leaders (sufficient state: greedy
    // NMS suppression comes only from kept boxes). R14-proven pattern.
    if (nkept < MAXDET) {
        u64 pmin = pminS;                              // pool = keys >= pmin
        int q0 = 0, q1 = 0;
        while (q0 < HALF && hk[q0] >= pmin) ++q0;
        while (q1 < HALF && hk[HALF + q1] >= pmin) ++q1;
        while (nkept < MAXDET) {
            u64 h0 = (q0 < HALF) ? hk[q0] : 0;
            u64 h1 = (q1 < HALF) ? hk[HALF + q1] : 0;
            u64 hmax = (h0 > h1) ? h0 : h1;
            if ((unsigned int)(hmax >> 32) == 0u) break;   // invalids sort last
            if (hmax == h0) ++q0; else ++q1;
            unsigned int idx = ~(unsigned int)hmax;
            float4 v = bb4[idx];
            float varea = (v.z - v.x) * (v.w - v.y);
            bool sup = false;
            for (int t = lane; t < nkept; t += 64) {
                float4 Lb = leadersB[t];
                float  La = leadersA[t];
                float iw = fminf(Lb.z, v.z) - fmaxf(Lb.x, v.x);
                float ih = fminf(Lb.w, v.w) - fmaxf(Lb.y, v.y);
                iw = fmaxf(iw, 0.0f);
                ih = fmaxf(ih, 0.0f);
                float inter = iw * ih;
                float denom = (La + varea) - inter;
                if ((double)inter > IOU_MID * (double)denom) sup = true;
            }
            if (__ballot(sup) == 0ULL) {
                if (lane == 0) {
                    float* rr = regions + ((size_t)(img * MAXDET + nkept)) * 5;
                    rr[0] = (float)img; rr[1] = v.x; rr[2] = v.y; rr[3] = v.z; rr[4] = v.w;
                    maskv[img * MAXDET + nkept] = 1.0f;
                    leadersB[nkept] = v;
                    leadersA[nkept] = varea;
                }
                nkept++;
            }
        }
    }

    // Padding fill (d_out is poisoned before every launch).
    for (int r = nkept + lane; r < MAXDET; r += 64) {
        float* rr = regions + ((size_t)(img * MAXDET + r)) * 5;
        rr[0] = (float)img; rr[1] = 0.0f; rr[2] = 0.0f; rr[3] = 0.0f; rr[4] = 0.0f;
        maskv[img * MAXDET + r] = 0.0f;
    }
}

extern "C" void kernel_launch(void* const* d_in, const int* in_sizes, int n_in,
                              void* d_out, int out_size, void* d_ws, size_t ws_size,
                              hipStream_t stream) {
    const float* boxes  = (const float*)d_in[0];  // [8,2048,4] f32
    const float* scores = (const float*)d_in[1];  // [8,2048]   f32
    float* out = (float*)d_out;                   // 4800 f32: regions(4000) ++ mask(800)
    u64* halfKeys = (u64*)d_ws;                   // 128 KB of workspace

    k_sort_half<<<16, 512, 0, stream>>>(boxes, scores, halfKeys);
    k_nms<<<NIMG, 1024, 0, stream>>>(boxes, halfKeys, out);
}